// Round 5
// baseline (6885.197 us; speedup 1.0000x reference)
//
#include <hip/hip_runtime.h>
#include <hip/hip_bf16.h>

#define B_ 32
#define T_ 512
#define D_ 1024
#define N_ 1024
#define NWG 192
#define NGATE 128
#define TPB 256
// LDS: weights [2][64][64][8] ushort = 131072 B, reduce 8*256 f32 = 8192 B, bias 64 B
#define SMEM_BYTES (131072 + 8192 + 64)

typedef __attribute__((ext_vector_type(8))) short short8v;
typedef __attribute__((ext_vector_type(4))) float f32x4;

__device__ __forceinline__ float bf2f(unsigned short u) {
  union { float f; unsigned int i; } c; c.i = ((unsigned int)u) << 16; return c.f;
}
__device__ __forceinline__ unsigned short f2bf(float f) {
  union { float f; unsigned int i; } c; c.f = f;
  unsigned int r = c.i + 0x7FFFu + ((c.i >> 16) & 1u);
  return (unsigned short)(r >> 16);
}

// ---- direct-to-LLC accessors (bypass L1+L2): cross-WG data only.
__device__ __forceinline__ void st_bf16_sc(unsigned short* p, unsigned short v) {
  asm volatile("global_store_short %0, %1, off sc0 sc1"
               :: "v"((unsigned long long)p), "v"((unsigned)v) : "memory");
}
__device__ __forceinline__ void st_f32_sc(float* p, float v) {
  asm volatile("global_store_dword %0, %1, off sc0 sc1"
               :: "v"((unsigned long long)p), "v"(v) : "memory");
}
// Waiting pair load (Round-3 proven): vmcnt(0) inside the asm, values valid on exit.
__device__ __forceinline__ void ld2_f32_sc(const float* p0, const float* p1,
                                           float& a, float& b) {
  asm volatile("global_load_dword %0, %2, off sc0 sc1\n\t"
               "global_load_dword %1, %3, off sc0 sc1\n\t"
               "s_waitcnt vmcnt(0)"
               : "=&v"(a), "=&v"(b)
               : "v"((unsigned long long)p0), "v"((unsigned long long)p1)
               : "memory");
}

// ---- partial grid barriers, 2-level tree, monotonic counters, 8 slots.
// A: 128 gate WGs arrive (8 leaf lines x 16), cand waits. B: 64 cand WGs arrive
// (4 leaf lines x 16), gates wait. Fence-free: all cross-WG data is LLC-direct
// (sc0 sc1); explicit vmcnt(0) before arrive drains the inline-asm stores.
template <int NL>
__device__ __forceinline__ void bar_arrive(unsigned* base, int bi, int line) {
  asm volatile("s_waitcnt vmcnt(0)" ::: "memory");
  __syncthreads();
  if (threadIdx.x == 0) {
    const int slot = bi & 7, epoch = bi >> 3;
    unsigned* L = base + (size_t)(slot * (NL + 1) + line) * 16;
    unsigned old = __hip_atomic_fetch_add(L, 1u, __ATOMIC_RELAXED, __HIP_MEMORY_SCOPE_AGENT);
    if (old == (unsigned)(epoch * 16 + 15)) {   // last arriver on this leaf line
      __hip_atomic_fetch_add(base + (size_t)(slot * (NL + 1) + NL) * 16, 1u,
                             __ATOMIC_RELAXED, __HIP_MEMORY_SCOPE_AGENT);
    }
  }
}
template <int NL>
__device__ __forceinline__ void bar_wait(unsigned* base, int bi) {
  if (threadIdx.x == 0) {
    const int slot = bi & 7;
    const unsigned tgt = (unsigned)(((bi >> 3) + 1) * NL);
    unsigned* R = base + (size_t)(slot * (NL + 1) + NL) * 16;
    int tries = 0;
    while (__hip_atomic_load(R, __ATOMIC_RELAXED, __HIP_MEMORY_SCOPE_AGENT) < tgt) {
      __builtin_amdgcn_s_sleep(1);
      if (++tries > (1 << 20)) break;  // deadlock valve; never hit normally
    }
  }
  __syncthreads();
}

// Fragment-order flat offset for [32 rows][1024 k] bf16 stored [mt][ks][lane][j].
__device__ __forceinline__ int frag_off(int m, int k) {
  const int mt = m >> 4, ks = k >> 5, kk = k & 31;
  const int l = (m & 15) + (((kk >> 2) & 3) << 4);
  const int j = (kk & 3) + ((kk >> 4) << 2);
  return ((mt * 32 + ks) * 64 + l) * 8 + j;
}

__device__ __forceinline__ short8v pack_frag(f32x4 lo, f32x4 hi) {
  short8v r;
  r[0] = (short)f2bf(lo[0]); r[1] = (short)f2bf(lo[1]);
  r[2] = (short)f2bf(lo[2]); r[3] = (short)f2bf(lo[3]);
  r[4] = (short)f2bf(hi[0]); r[5] = (short)f2bf(hi[1]);
  r[6] = (short)f2bf(hi[2]); r[7] = (short)f2bf(hi[3]);
  return r;
}

// Build A-fragments for x_t directly from global f32 (read-only input: plain
// cached loads, no coherence needed). Same f2bf RNE as prior rounds.
template <int KS>
__device__ __forceinline__ void build_xfrags(const float* __restrict__ x, int t,
                                             int kbase, int lane,
                                             short8v frag[2][KS]) {
#pragma unroll
  for (int mt = 0; mt < 2; ++mt) {
    const int m = mt * 16 + (lane & 15);
    const float* row = x + ((size_t)m * T_ + t) * D_;
#pragma unroll
    for (int ks = 0; ks < KS; ++ks) {
      const int k0 = kbase + ks * 32 + ((lane >> 4) << 2);
      f32x4 lo = *(const f32x4*)(row + k0);
      f32x4 hi = *(const f32x4*)(row + k0 + 16);
      frag[mt][ks] = pack_frag(lo, hi);
    }
  }
}

// MFMA over KS k-steps, A from registers; B from LDS (frag order, hi/lo split).
template <int KS>
__device__ __forceinline__ void mfma_reg(const short8v frag[2][KS],
                                         const unsigned short* __restrict__ ldsW,
                                         int ksg0, f32x4* acc, int lane) {
#pragma unroll
  for (int mt = 0; mt < 2; ++mt)
#pragma unroll
    for (int ks = 0; ks < KS; ++ks) {
      const int ksg = ksg0 + ks;
      short8v bhi = *(const short8v*)(ldsW + ((size_t)(0 * 64 + ksg) * 64 + lane) * 8);
      short8v blo = *(const short8v*)(ldsW + ((size_t)(1 * 64 + ksg) * 64 + lane) * 8);
      acc[mt] = __builtin_amdgcn_mfma_f32_16x16x32_bf16(frag[mt][ks], bhi, acc[mt], 0, 0, 0);
      acc[mt] = __builtin_amdgcn_mfma_f32_16x16x32_bf16(frag[mt][ks], blo, acc[mt], 0, 0, 0);
    }
}

// MFMA over KS k-steps, A loaded LLC-direct from a fragment-ordered buffer.
template <int KS>
__device__ __forceinline__ void mfma_llc(const unsigned short* __restrict__ fragbuf,
                                         int ks0,
                                         const unsigned short* __restrict__ ldsW,
                                         int ksg0, f32x4* acc, int lane) {
  short8v areg[2][KS];
#pragma unroll
  for (int mt = 0; mt < 2; ++mt)
#pragma unroll
    for (int ks = 0; ks < KS; ++ks) {
      const unsigned short* p =
          fragbuf + ((size_t)((mt * 32 + ks0 + ks) * 64 + lane)) * 8;
      asm volatile("global_load_dwordx4 %0, %1, off sc0 sc1"
                   : "=v"(areg[mt][ks]) : "v"((unsigned long long)p) : "memory");
    }
  asm volatile("s_waitcnt vmcnt(0)" ::: "memory");
  __builtin_amdgcn_sched_barrier(0);  // rule #18: nothing crosses the waitcnt
#pragma unroll
  for (int mt = 0; mt < 2; ++mt)
#pragma unroll
    for (int ks = 0; ks < KS; ++ks) {
      const int ksg = ksg0 + ks;
      short8v bhi = *(const short8v*)(ldsW + ((size_t)(0 * 64 + ksg) * 64 + lane) * 8);
      short8v blo = *(const short8v*)(ldsW + ((size_t)(1 * 64 + ksg) * 64 + lane) * 8);
      acc[mt] = __builtin_amdgcn_mfma_f32_16x16x32_bf16(areg[mt][ks], bhi, acc[mt], 0, 0, 0);
      acc[mt] = __builtin_amdgcn_mfma_f32_16x16x32_bf16(areg[mt][ks], blo, acc[mt], 0, 0, 0);
    }
}

__global__ __launch_bounds__(TPB, 1) void gru_persistent(
    const float* __restrict__ x, const float* __restrict__ h0,
    const float* __restrict__ Wg, const float* __restrict__ bg,
    const float* __restrict__ Wc, const float* __restrict__ bc,
    float* __restrict__ out,
    unsigned* __restrict__ ctrs,
    unsigned short* __restrict__ hq,     // [frag 32x1024] bf16 h
    unsigned short* __restrict__ rhq,    // [frag 32x1024] bf16 r*h
    float* __restrict__ u_buf,           // [32][1024] f32 u gate
    float* __restrict__ h_buf)           // [32][1024] f32 h (for r-gate readers)
{
  const int wg = blockIdx.x;
  const int tid = threadIdx.x;
  const int lane = tid & 63;
  const int wv = tid >> 6;

  extern __shared__ char smem[];
  unsigned short* ldsW = (unsigned short*)smem;            // [2][64][64][8]
  float* ldsR = (float*)(smem + 131072);                   // [8][256]
  float* ldsBias = (float*)(smem + 131072 + 8192);         // [16]

  unsigned* ctrA = ctrs;                 // 8 slots * 9 lines * 64B
  unsigned* ctrB = ctrs + 72 * 16;       // 8 slots * 5 lines * 64B

  const bool is_gate = wg < NGATE;
  const int c0 = (is_gate ? wg : (wg - NGATE)) * 16;
  const float* Wsrc = is_gate ? Wg : Wc;
  const int ldw = is_gate ? 2 * N_ : N_;
  const float* bias = is_gate ? bg : bc;

  const int col = tid & 15, row = tid >> 4;
  const int colg = c0 + col;
  const int b0 = row, b1 = 16 + row;

  // ---- preload weight slice into LDS in MFMA-fragment order, hi/lo split bf16
  for (int i = tid; i < 64 * 64; i += TPB) {
    const int ks = i >> 6, l = i & 63;
    const int n = l & 15, kqp = (l >> 4) * 4;
#pragma unroll
    for (int j = 0; j < 8; ++j) {
      const int k = ks * 32 + ((j < 4) ? 0 : 16) + kqp + (j & 3);
      const float w = Wsrc[(size_t)k * ldw + c0 + n];
      const unsigned short hi = f2bf(w);
      const unsigned short lo = f2bf(w - bf2f(hi));
      ldsW[((size_t)(0 * 64 + ks) * 64 + l) * 8 + j] = hi;
      ldsW[((size_t)(1 * 64 + ks) * 64 + l) * 8 + j] = lo;
    }
  }
  if (tid < 16) ldsBias[tid] = bias[c0 + tid];
  __syncthreads();

  if (is_gate) {
    const bool r_wg = (c0 < N_);
    for (int t = 0; t < T_; ++t) {
      bar_wait<4>(ctrB, t);               // h(t-1) ready (t=0: cand init)
      float hv0 = 0.f, hv1 = 0.f;
      if (r_wg)                           // waiting load: values valid after call
        ld2_f32_sc(h_buf + b0 * N_ + colg, h_buf + b1 * N_ + colg, hv0, hv1);
      f32x4 acc[2] = {{0.f,0.f,0.f,0.f},{0.f,0.f,0.f,0.f}};
      if (wv < 2) {                       // x_t @ Wg[k<1024], per-iteration frags
        short8v xf[2][16];
        build_xfrags<16>(x, t, wv * 512, lane, xf);
        mfma_reg<16>(xf, ldsW, wv * 16, acc, lane);
      } else {                            // h @ Wg[k>=1024], LLC-direct
        mfma_llc<16>(hq, (wv - 2) * 16, ldsW, 32 + (wv - 2) * 16, acc, lane);
      }
#pragma unroll
      for (int mt = 0; mt < 2; ++mt)
#pragma unroll
        for (int r = 0; r < 4; ++r)
          ldsR[(wv * 2 + mt) * 256 + (4 * (lane >> 4) + r) * 16 + (lane & 15)] = acc[mt][r];
      __syncthreads();
      {
        float s0 = ldsR[0 * 256 + tid] + ldsR[2 * 256 + tid]
                 + ldsR[4 * 256 + tid] + ldsR[6 * 256 + tid];
        float s1 = ldsR[1 * 256 + tid] + ldsR[3 * 256 + tid]
                 + ldsR[5 * 256 + tid] + ldsR[7 * 256 + tid];
        float p0 = fminf(fmaxf(s0 + ldsBias[col], -30.f), 30.f);
        float p1 = fminf(fmaxf(s1 + ldsBias[col], -30.f), 30.f);
        const float g0 = 1.f / (1.f + __expf(-p0));
        const float g1 = 1.f / (1.f + __expf(-p1));
        if (r_wg) {
          st_bf16_sc(rhq + frag_off(b0, colg), f2bf(g0 * hv0));
          st_bf16_sc(rhq + frag_off(b1, colg), f2bf(g1 * hv1));
        } else {
          st_f32_sc(u_buf + b0 * N_ + (colg - N_), g0);
          st_f32_sc(u_buf + b1 * N_ + (colg - N_), g1);
        }
      }
      bar_arrive<8>(ctrA, t, wg >> 4);
    }
  } else {
    const int cidx = wg - NGATE;          // 0..63
    // ---- init state t=-1: h0 into regs + h_buf(f32) + hq(bf16 frags)
    float hreg0 = h0[b0 * N_ + colg];
    float hreg1 = h0[b1 * N_ + colg];
    st_f32_sc(h_buf + b0 * N_ + colg, hreg0);
    st_f32_sc(h_buf + b1 * N_ + colg, hreg1);
    st_bf16_sc(hq + frag_off(b0, colg), f2bf(hreg0));
    st_bf16_sc(hq + frag_off(b1, colg), f2bf(hreg1));
    bar_arrive<4>(ctrB, 0, cidx >> 4);

    f32x4 acc[2] = {{0.f,0.f,0.f,0.f},{0.f,0.f,0.f,0.f}};
    {  // partA(t=0): x0 @ Wc[k<1024], K=256 per wave, from global f32
      short8v xf[2][8];
      build_xfrags<8>(x, 0, wv * 256, lane, xf);
      mfma_reg<8>(xf, ldsW, wv * 8, acc, lane);
    }
    for (int t = 0; t < T_; ++t) {
      bar_wait<8>(ctrA, t);               // rhq, u ready
      float uv0, uv1;                     // waiting load: valid after call
      ld2_f32_sc(u_buf + b0 * N_ + colg, u_buf + b1 * N_ + colg, uv0, uv1);
      // partB (critical path): (r*h) @ Wc[k>=1024], K=256 per wave
      mfma_llc<8>(rhq, wv * 8, ldsW, 32 + wv * 8, acc, lane);
#pragma unroll
      for (int mt = 0; mt < 2; ++mt)
#pragma unroll
        for (int r = 0; r < 4; ++r)
          ldsR[(wv * 2 + mt) * 256 + (4 * (lane >> 4) + r) * 16 + (lane & 15)] = acc[mt][r];
      __syncthreads();
      {
        float s0 = ldsR[0 * 256 + tid] + ldsR[2 * 256 + tid]
                 + ldsR[4 * 256 + tid] + ldsR[6 * 256 + tid];
        float s1 = ldsR[1 * 256 + tid] + ldsR[3 * 256 + tid]
                 + ldsR[5 * 256 + tid] + ldsR[7 * 256 + tid];
        float p0 = fminf(fmaxf(s0 + ldsBias[col], -20.f), 20.f);
        float p1 = fminf(fmaxf(s1 + ldsBias[col], -20.f), 20.f);
        const float e0 = __expf(2.f * p0), e1 = __expf(2.f * p1);
        const float c0v = (e0 - 1.f) / (e0 + 1.f);       // tanh
        const float c1v = (e1 - 1.f) / (e1 + 1.f);
        const float hn0 = uv0 * hreg0 + (1.f - uv0) * c0v;
        const float hn1 = uv1 * hreg1 + (1.f - uv1) * c1v;
        hreg0 = hn0; hreg1 = hn1;
        st_bf16_sc(hq + frag_off(b0, colg), f2bf(hn0));   // critical stores first
        st_bf16_sc(hq + frag_off(b1, colg), f2bf(hn1));
        st_f32_sc(h_buf + b0 * N_ + colg, hn0);
        st_f32_sc(h_buf + b1 * N_ + colg, hn1);
        out[((size_t)b0 * T_ + t) * N_ + colg] = hn0;     // cached (host-only reader)
        out[((size_t)b1 * T_ + t) * N_ + colg] = hn1;
      }
      bar_arrive<4>(ctrB, t + 1, cidx >> 4);
      if (t + 1 < T_) {                   // off critical path: partA(t+1)
        acc[0] = (f32x4){0.f,0.f,0.f,0.f};
        acc[1] = (f32x4){0.f,0.f,0.f,0.f};
        short8v xf[2][8];
        build_xfrags<8>(x, t + 1, wv * 256, lane, xf);
        mfma_reg<8>(xf, ldsW, wv * 8, acc, lane);
      }
    }
  }
}

extern "C" void kernel_launch(void* const* d_in, const int* in_sizes, int n_in,
                              void* d_out, int out_size, void* d_ws, size_t ws_size,
                              hipStream_t stream) {
  const float* x  = (const float*)d_in[0];
  const float* h0 = (const float*)d_in[1];
  const float* Wg = (const float*)d_in[2];
  const float* bg = (const float*)d_in[3];
  const float* Wc = (const float*)d_in[4];
  const float* bc = (const float*)d_in[5];
  float* out = (float*)d_out;

  char* w = (char*)d_ws;
  unsigned* ctrs       = (unsigned*)(w + 0);             // 112 lines*64B = 7168 (reserve 8192)
  unsigned short* hq   = (unsigned short*)(w + 8192);    // 65536
  unsigned short* rhq  = (unsigned short*)(w + 73728);   // 65536
  float* u_buf         = (float*)(w + 139264);           // 131072
  float* h_buf         = (float*)(w + 270336);           // 131072 -> total 401408 B

  hipFuncSetAttribute((const void*)gru_persistent,
                      hipFuncAttributeMaxDynamicSharedMemorySize, SMEM_BYTES);
  hipMemsetAsync(w, 0, 8192, stream);  // zero barrier counters each launch
  gru_persistent<<<NWG, TPB, SMEM_BYTES, stream>>>(
      x, h0, Wg, bg, Wc, bc, out, ctrs, hq, rhq, u_buf, h_buf);
}

// Round 6
// 3664.182 us; speedup vs baseline: 1.8791x; 1.8791x over previous
//
#include <hip/hip_runtime.h>
#include <hip/hip_bf16.h>

#define B_ 32
#define T_ 512
#define D_ 1024
#define N_ 1024
#define NWG 192
#define NGATE 128
#define TPB 256
// LDS: weights 131072 + reduce 8192 + bias 64 + ldsH 16*33*4=2112
#define SMEM_BYTES (131072 + 8192 + 64 + 2112)

typedef __attribute__((ext_vector_type(8))) short short8v;
typedef __attribute__((ext_vector_type(4))) float f32x4;

__device__ __forceinline__ float bf2f(unsigned short u) {
  union { float f; unsigned int i; } c; c.i = ((unsigned int)u) << 16; return c.f;
}
__device__ __forceinline__ unsigned short f2bf(float f) {   // software RNE (weights)
  union { float f; unsigned int i; } c; c.f = f;
  unsigned int r = c.i + 0x7FFFu + ((c.i >> 16) & 1u);
  return (unsigned short)(r >> 16);
}
// HW packed f32->bf16 RNE: 2 elems / instruction (activation conversions)
__device__ __forceinline__ unsigned cvtpk(float a, float b) {
  unsigned r;
  asm("v_cvt_pk_bf16_f32 %0, %1, %2" : "=v"(r) : "v"(a), "v"(b));
  return r;
}
__device__ __forceinline__ short8v pack_frag(f32x4 lo, f32x4 hi) {
  union { unsigned u[4]; short8v s; } c;
  c.u[0] = cvtpk(lo[0], lo[1]); c.u[1] = cvtpk(lo[2], lo[3]);
  c.u[2] = cvtpk(hi[0], hi[1]); c.u[3] = cvtpk(hi[2], hi[3]);
  return c.s;
}

// ---- direct-to-LLC accessors (bypass L1+L2): all cross-WG data.
__device__ __forceinline__ void st_bf16_sc(unsigned short* p, unsigned short v) {
  asm volatile("global_store_short %0, %1, off sc0 sc1"
               :: "v"((unsigned long long)p), "v"((unsigned)v) : "memory");
}
__device__ __forceinline__ void st_f32_sc(float* p, float v) {
  asm volatile("global_store_dword %0, %1, off sc0 sc1"
               :: "v"((unsigned long long)p), "v"(v) : "memory");
}

// ---- point-to-point epoch flags (single writer per 64B line, monotonic).
// Writer: [data sc1 stores] -> vmcnt(0) -> __syncthreads -> relaxed agent store.
// Reader: relaxed agent poll -> sc1 data loads. LLC is the common serialization
// point (protocol proven R3/R5).
__device__ __forceinline__ void flag_store(unsigned* line, unsigned v) {
  __hip_atomic_store(line, v, __ATOMIC_RELAXED, __HIP_MEMORY_SCOPE_AGENT);
}
// wave polls 64 lines (lane l -> line l) until all >= tgt
__device__ __forceinline__ void poll64(unsigned* base, int lane, unsigned tgt) {
  unsigned* p = base + (size_t)lane * 16;
  int tries = 0;
  for (;;) {
    unsigned v = __hip_atomic_load(p, __ATOMIC_RELAXED, __HIP_MEMORY_SCOPE_AGENT);
    if (__all((int)(v >= tgt))) break;
    __builtin_amdgcn_s_sleep(1);
    if (++tries > (1 << 20)) break;   // deadlock valve; never hit normally
  }
}
// wave polls 128 lines (lane l -> lines l and 64+l) until all >= tgt
__device__ __forceinline__ void poll128(unsigned* base, int lane, unsigned tgt) {
  unsigned* p0 = base + (size_t)lane * 16;
  unsigned* p1 = base + (size_t)(64 + lane) * 16;
  int tries = 0;
  for (;;) {
    unsigned v0 = __hip_atomic_load(p0, __ATOMIC_RELAXED, __HIP_MEMORY_SCOPE_AGENT);
    unsigned v1 = __hip_atomic_load(p1, __ATOMIC_RELAXED, __HIP_MEMORY_SCOPE_AGENT);
    if (__all((int)(v0 >= tgt && v1 >= tgt))) break;
    __builtin_amdgcn_s_sleep(1);
    if (++tries > (1 << 20)) break;
  }
}

// Fragment-order flat offset for [32 rows][1024 k] bf16 stored [mt][ks][lane][j].
__device__ __forceinline__ int frag_off(int m, int k) {
  const int mt = m >> 4, ks = k >> 5, kk = k & 31;
  const int l = (m & 15) + (((kk >> 2) & 3) << 4);
  const int j = (kk & 3) + ((kk >> 4) << 2);
  return ((mt * 32 + ks) * 64 + l) * 8 + j;
}

// Build A-fragments for x_t from global f32 (read-only input: plain cached loads).
template <int KS>
__device__ __forceinline__ void build_xfrags(const float* __restrict__ x, int t,
                                             int kbase, int lane,
                                             short8v frag[2][KS]) {
#pragma unroll
  for (int mt = 0; mt < 2; ++mt) {
    const int m = mt * 16 + (lane & 15);
    const float* row = x + ((size_t)m * T_ + t) * D_;
#pragma unroll
    for (int ks = 0; ks < KS; ++ks) {
      const int k0 = kbase + ks * 32 + ((lane >> 4) << 2);
      f32x4 lo = *(const f32x4*)(row + k0);
      f32x4 hi = *(const f32x4*)(row + k0 + 16);
      frag[mt][ks] = pack_frag(lo, hi);
    }
  }
}

// MFMA over KS k-steps, A from registers; B from LDS (frag order, hi/lo split).
template <int KS>
__device__ __forceinline__ void mfma_reg(const short8v frag[2][KS],
                                         const unsigned short* __restrict__ ldsW,
                                         int ksg0, f32x4* acc, int lane) {
#pragma unroll
  for (int mt = 0; mt < 2; ++mt)
#pragma unroll
    for (int ks = 0; ks < KS; ++ks) {
      const int ksg = ksg0 + ks;
      short8v bhi = *(const short8v*)(ldsW + ((size_t)(0 * 64 + ksg) * 64 + lane) * 8);
      short8v blo = *(const short8v*)(ldsW + ((size_t)(1 * 64 + ksg) * 64 + lane) * 8);
      acc[mt] = __builtin_amdgcn_mfma_f32_16x16x32_bf16(frag[mt][ks], bhi, acc[mt], 0, 0, 0);
      acc[mt] = __builtin_amdgcn_mfma_f32_16x16x32_bf16(frag[mt][ks], blo, acc[mt], 0, 0, 0);
    }
}

// Gate waves 2,3: one issue-batch {optional h dwordx4} + {16 hq dwordx4}, one
// vmcnt(0), then the MFMA chain. Single LLC round trip for the whole phase.
__device__ __forceinline__ void gate_hphase(
    const unsigned short* __restrict__ hq, int ks0,
    const unsigned short* __restrict__ ldsW, int ksg0,
    f32x4* acc, int lane, bool loadh, const float* __restrict__ hsrc, f32x4& hvec)
{
  short8v areg[2][16];
  if (loadh)                               // wave-uniform branch
    asm volatile("global_load_dwordx4 %0, %1, off sc0 sc1"
                 : "=v"(hvec) : "v"((unsigned long long)hsrc) : "memory");
#pragma unroll
  for (int mt = 0; mt < 2; ++mt)
#pragma unroll
    for (int ks = 0; ks < 16; ++ks) {
      const unsigned short* p = hq + ((size_t)((mt * 32 + ks0 + ks) * 64 + lane)) * 8;
      asm volatile("global_load_dwordx4 %0, %1, off sc0 sc1"
                   : "=v"(areg[mt][ks]) : "v"((unsigned long long)p) : "memory");
    }
  asm volatile("s_waitcnt vmcnt(0)" ::: "memory");
  __builtin_amdgcn_sched_barrier(0);       // rule #18
#pragma unroll
  for (int mt = 0; mt < 2; ++mt)
#pragma unroll
    for (int ks = 0; ks < 16; ++ks) {
      const int ksg = ksg0 + ks;
      short8v bhi = *(const short8v*)(ldsW + ((size_t)(0 * 64 + ksg) * 64 + lane) * 8);
      short8v blo = *(const short8v*)(ldsW + ((size_t)(1 * 64 + ksg) * 64 + lane) * 8);
      acc[mt] = __builtin_amdgcn_mfma_f32_16x16x32_bf16(areg[mt][ks], bhi, acc[mt], 0, 0, 0);
      acc[mt] = __builtin_amdgcn_mfma_f32_16x16x32_bf16(areg[mt][ks], blo, acc[mt], 0, 0, 0);
    }
}

// Cand partB: one issue-batch {2 u dwords} + {16 rhq dwordx4}, one vmcnt(0), MFMA.
__device__ __forceinline__ void cand_bphase(
    const unsigned short* __restrict__ rhq, int ks0,
    const unsigned short* __restrict__ ldsW, int ksg0,
    f32x4* acc, int lane,
    const float* up0, const float* up1, float& uv0, float& uv1)
{
  short8v areg[2][8];
  asm volatile("global_load_dword %0, %2, off sc0 sc1\n\t"
               "global_load_dword %1, %3, off sc0 sc1"
               : "=&v"(uv0), "=&v"(uv1)
               : "v"((unsigned long long)up0), "v"((unsigned long long)up1)
               : "memory");
#pragma unroll
  for (int mt = 0; mt < 2; ++mt)
#pragma unroll
    for (int ks = 0; ks < 8; ++ks) {
      const unsigned short* p = rhq + ((size_t)((mt * 32 + ks0 + ks) * 64 + lane)) * 8;
      asm volatile("global_load_dwordx4 %0, %1, off sc0 sc1"
                   : "=v"(areg[mt][ks]) : "v"((unsigned long long)p) : "memory");
    }
  asm volatile("s_waitcnt vmcnt(0)" ::: "memory");
  __builtin_amdgcn_sched_barrier(0);
#pragma unroll
  for (int mt = 0; mt < 2; ++mt)
#pragma unroll
    for (int ks = 0; ks < 8; ++ks) {
      const int ksg = ksg0 + ks;
      short8v bhi = *(const short8v*)(ldsW + ((size_t)(0 * 64 + ksg) * 64 + lane) * 8);
      short8v blo = *(const short8v*)(ldsW + ((size_t)(1 * 64 + ksg) * 64 + lane) * 8);
      acc[mt] = __builtin_amdgcn_mfma_f32_16x16x32_bf16(areg[mt][ks], bhi, acc[mt], 0, 0, 0);
      acc[mt] = __builtin_amdgcn_mfma_f32_16x16x32_bf16(areg[mt][ks], blo, acc[mt], 0, 0, 0);
    }
}

__global__ __launch_bounds__(TPB, 1) void gru_persistent(
    const float* __restrict__ x, const float* __restrict__ h0,
    const float* __restrict__ Wg, const float* __restrict__ bg,
    const float* __restrict__ Wc, const float* __restrict__ bc,
    float* __restrict__ out,
    unsigned* __restrict__ ctrs,
    unsigned short* __restrict__ hq,     // [frag 32x1024] bf16 h
    unsigned short* __restrict__ rhq,    // [frag 32x1024] bf16 r*h
    float* __restrict__ u_buf,           // [32][1024] f32 u gate
    float* __restrict__ h_buf)           // TRANSPOSED [1024 col][32 b] f32 h
{
  const int wg = blockIdx.x;
  const int tid = threadIdx.x;
  const int lane = tid & 63;
  const int wv = tid >> 6;

  extern __shared__ char smem[];
  unsigned short* ldsW = (unsigned short*)smem;            // [2][64][64][8]
  float* ldsR = (float*)(smem + 131072);                   // [8][256]
  float* ldsBias = (float*)(smem + 131072 + 8192);         // [16]
  float* ldsH = (float*)(smem + 131072 + 8192 + 64);       // [16][33]

  unsigned* flagH = ctrs;                  // 64 lines: cand WG j -> h(t) epochs
  unsigned* flagG = ctrs + 64 * 16;        // 128 lines: gate WG i -> rhq/u epochs

  const bool is_gate = wg < NGATE;
  const int c0 = (is_gate ? wg : (wg - NGATE)) * 16;
  const float* Wsrc = is_gate ? Wg : Wc;
  const int ldw = is_gate ? 2 * N_ : N_;
  const float* bias = is_gate ? bg : bc;

  const int col = tid & 15, row = tid >> 4;
  const int colg = c0 + col;
  const int b0 = row, b1 = 16 + row;

  // ---- preload weight slice into LDS in MFMA-fragment order, hi/lo split bf16
  for (int i = tid; i < 64 * 64; i += TPB) {
    const int ks = i >> 6, l = i & 63;
    const int n = l & 15, kqp = (l >> 4) * 4;
#pragma unroll
    for (int j = 0; j < 8; ++j) {
      const int k = ks * 32 + ((j < 4) ? 0 : 16) + kqp + (j & 3);
      const float w = Wsrc[(size_t)k * ldw + c0 + n];
      const unsigned short hi = f2bf(w);
      const unsigned short lo = f2bf(w - bf2f(hi));
      ldsW[((size_t)(0 * 64 + ks) * 64 + l) * 8 + j] = hi;
      ldsW[((size_t)(1 * 64 + ks) * 64 + l) * 8 + j] = lo;
    }
  }
  if (tid < 16) ldsBias[tid] = bias[c0 + tid];
  __syncthreads();

  if (is_gate) {
    const bool r_wg = (c0 < N_);
    unsigned* myflag = flagG + (size_t)wg * 16;
    for (int t = 0; t < T_; ++t) {
      f32x4 acc[2] = {{0.f,0.f,0.f,0.f},{0.f,0.f,0.f,0.f}};
      f32x4 hvec = {0.f,0.f,0.f,0.f};
      if (wv < 2) {
        // x @ Wg[k<1024] — no dependency: starts during waves 2,3's poll+RT
        short8v xf[2][16];
        build_xfrags<16>(x, t, wv * 512, lane, xf);
        mfma_reg<16>(xf, ldsW, wv * 16, acc, lane);
      } else {
        poll64(flagH, lane, (unsigned)(t + 1));      // h(t-1) ready
        const int idx = tid - 128;                   // 0..127
        const float* hsrc = h_buf + (size_t)(c0 + (idx & 15)) * 32 + (idx >> 4) * 4;
        gate_hphase(hq, (wv - 2) * 16, ldsW, 32 + (wv - 2) * 16, acc, lane,
                    r_wg, hsrc, hvec);
        if (r_wg) {                                  // stage h for epilogue
          float* d = ldsH + (idx & 15) * 33 + (idx >> 4) * 4;
          d[0] = hvec[0]; d[1] = hvec[1]; d[2] = hvec[2]; d[3] = hvec[3];
        }
      }
#pragma unroll
      for (int mt = 0; mt < 2; ++mt)
#pragma unroll
        for (int r = 0; r < 4; ++r)
          ldsR[(wv * 2 + mt) * 256 + (4 * (lane >> 4) + r) * 16 + (lane & 15)] = acc[mt][r];
      __syncthreads();
      {
        float s0 = ldsR[0 * 256 + tid] + ldsR[2 * 256 + tid]
                 + ldsR[4 * 256 + tid] + ldsR[6 * 256 + tid];
        float s1 = ldsR[1 * 256 + tid] + ldsR[3 * 256 + tid]
                 + ldsR[5 * 256 + tid] + ldsR[7 * 256 + tid];
        float p0 = fminf(fmaxf(s0 + ldsBias[col], -30.f), 30.f);
        float p1 = fminf(fmaxf(s1 + ldsBias[col], -30.f), 30.f);
        const float g0 = 1.f / (1.f + __expf(-p0));
        const float g1 = 1.f / (1.f + __expf(-p1));
        if (r_wg) {
          const float hv0 = ldsH[col * 33 + row];
          const float hv1 = ldsH[col * 33 + row + 16];
          st_bf16_sc(rhq + frag_off(b0, colg), f2bf(g0 * hv0));
          st_bf16_sc(rhq + frag_off(b1, colg), f2bf(g1 * hv1));
        } else {
          st_f32_sc(u_buf + b0 * N_ + (colg - N_), g0);
          st_f32_sc(u_buf + b1 * N_ + (colg - N_), g1);
        }
      }
      asm volatile("s_waitcnt vmcnt(0)" ::: "memory");
      __syncthreads();                    // also separates LDS reads from next-iter writes
      if (tid == 0) flag_store(myflag, (unsigned)(t + 1));
    }
  } else {
    unsigned* myflag = flagH + (size_t)(wg - NGATE) * 16;
    // ---- init h(-1)=h0: regs + transposed h_buf + hq frags; publish flag=1
    float hreg0 = h0[b0 * N_ + colg];
    float hreg1 = h0[b1 * N_ + colg];
    st_f32_sc(h_buf + (size_t)colg * 32 + b0, hreg0);
    st_f32_sc(h_buf + (size_t)colg * 32 + b1, hreg1);
    st_bf16_sc(hq + frag_off(b0, colg), f2bf(hreg0));
    st_bf16_sc(hq + frag_off(b1, colg), f2bf(hreg1));
    asm volatile("s_waitcnt vmcnt(0)" ::: "memory");
    __syncthreads();
    if (tid == 0) flag_store(myflag, 1u);

    f32x4 acc[2] = {{0.f,0.f,0.f,0.f},{0.f,0.f,0.f,0.f}};
    {  // partA(t=0): x0 @ Wc[k<1024]
      short8v xf[2][8];
      build_xfrags<8>(x, 0, wv * 256, lane, xf);
      mfma_reg<8>(xf, ldsW, wv * 8, acc, lane);
    }
    for (int t = 0; t < T_; ++t) {
      poll128(flagG, lane, (unsigned)(t + 1));       // rhq + u ready
      float uv0, uv1;
      cand_bphase(rhq, wv * 8, ldsW, 32 + wv * 8, acc, lane,
                  u_buf + b0 * N_ + colg, u_buf + b1 * N_ + colg, uv0, uv1);
#pragma unroll
      for (int mt = 0; mt < 2; ++mt)
#pragma unroll
        for (int r = 0; r < 4; ++r)
          ldsR[(wv * 2 + mt) * 256 + (4 * (lane >> 4) + r) * 16 + (lane & 15)] = acc[mt][r];
      __syncthreads();
      {
        float s0 = ldsR[0 * 256 + tid] + ldsR[2 * 256 + tid]
                 + ldsR[4 * 256 + tid] + ldsR[6 * 256 + tid];
        float s1 = ldsR[1 * 256 + tid] + ldsR[3 * 256 + tid]
                 + ldsR[5 * 256 + tid] + ldsR[7 * 256 + tid];
        float p0 = fminf(fmaxf(s0 + ldsBias[col], -20.f), 20.f);
        float p1 = fminf(fmaxf(s1 + ldsBias[col], -20.f), 20.f);
        const float e0 = __expf(2.f * p0), e1 = __expf(2.f * p1);
        const float c0v = (e0 - 1.f) / (e0 + 1.f);   // tanh
        const float c1v = (e1 - 1.f) / (e1 + 1.f);
        const float hn0 = uv0 * hreg0 + (1.f - uv0) * c0v;
        const float hn1 = uv1 * hreg1 + (1.f - uv1) * c1v;
        hreg0 = hn0; hreg1 = hn1;
        st_bf16_sc(hq + frag_off(b0, colg), f2bf(hn0));
        st_bf16_sc(hq + frag_off(b1, colg), f2bf(hn1));
        st_f32_sc(h_buf + (size_t)colg * 32 + b0, hn0);
        st_f32_sc(h_buf + (size_t)colg * 32 + b1, hn1);
        out[((size_t)b0 * T_ + t) * N_ + colg] = hn0;   // cached (host-only reader)
        out[((size_t)b1 * T_ + t) * N_ + colg] = hn1;
      }
      asm volatile("s_waitcnt vmcnt(0)" ::: "memory");
      __syncthreads();
      if (tid == 0) flag_store(myflag, (unsigned)(t + 2));
      if (t + 1 < T_) {                   // partA(t+1) in the gate-phase shadow
        acc[0] = (f32x4){0.f,0.f,0.f,0.f};
        acc[1] = (f32x4){0.f,0.f,0.f,0.f};
        short8v xf[2][8];
        build_xfrags<8>(x, t + 1, wv * 256, lane, xf);
        mfma_reg<8>(xf, ldsW, wv * 8, acc, lane);
      }
    }
  }
}

extern "C" void kernel_launch(void* const* d_in, const int* in_sizes, int n_in,
                              void* d_out, int out_size, void* d_ws, size_t ws_size,
                              hipStream_t stream) {
  const float* x  = (const float*)d_in[0];
  const float* h0 = (const float*)d_in[1];
  const float* Wg = (const float*)d_in[2];
  const float* bg = (const float*)d_in[3];
  const float* Wc = (const float*)d_in[4];
  const float* bc = (const float*)d_in[5];
  float* out = (float*)d_out;

  char* w = (char*)d_ws;
  unsigned* ctrs       = (unsigned*)(w + 0);             // 192 lines*64B = 12288 (reserve 16384)
  unsigned short* hq   = (unsigned short*)(w + 16384);   // 65536
  unsigned short* rhq  = (unsigned short*)(w + 81920);   // 65536
  float* u_buf         = (float*)(w + 147456);           // 131072
  float* h_buf         = (float*)(w + 278528);           // 131072 -> total 409600 B

  hipFuncSetAttribute((const void*)gru_persistent,
                      hipFuncAttributeMaxDynamicSharedMemorySize, SMEM_BYTES);
  hipMemsetAsync(w, 0, 16384, stream);  // zero flag lines each launch
  gru_persistent<<<NWG, TPB, SMEM_BYTES, stream>>>(
      x, h0, Wg, bg, Wc, bc, out, ctrs, hq, rhq, u_buf, h_buf);
}

// Round 7
// 3243.913 us; speedup vs baseline: 2.1225x; 1.1296x over previous
//
#include <hip/hip_runtime.h>
#include <hip/hip_bf16.h>

#define B_ 32
#define T_ 512
#define D_ 1024
#define N_ 1024
#define NWG 192
#define NGATE 128
#define TPB 256
// LDS: weights 131072 + reduce 8192 + bias 64 + ldsH 16*33*4=2112
#define SMEM_BYTES (131072 + 8192 + 64 + 2112)

typedef __attribute__((ext_vector_type(8))) short short8v;
typedef __attribute__((ext_vector_type(4))) float f32x4;

__device__ __forceinline__ float bf2f(unsigned short u) {
  union { float f; unsigned int i; } c; c.i = ((unsigned int)u) << 16; return c.f;
}
__device__ __forceinline__ unsigned short f2bf(float f) {   // software RNE (scalar)
  union { float f; unsigned int i; } c; c.f = f;
  unsigned int r = c.i + 0x7FFFu + ((c.i >> 16) & 1u);
  return (unsigned short)(r >> 16);
}
// HW packed f32->bf16 RNE: 2 elems / instruction (bulk activation conversions)
__device__ __forceinline__ unsigned cvtpk(float a, float b) {
  unsigned r;
  asm("v_cvt_pk_bf16_f32 %0, %1, %2" : "=v"(r) : "v"(a), "v"(b));
  return r;
}
__device__ __forceinline__ short8v pack_frag(f32x4 lo, f32x4 hi) {
  union { unsigned u[4]; short8v s; } c;
  c.u[0] = cvtpk(lo[0], lo[1]); c.u[1] = cvtpk(lo[2], lo[3]);
  c.u[2] = cvtpk(hi[0], hi[1]); c.u[3] = cvtpk(hi[2], hi[3]);
  return c.s;
}

// ---- direct-to-LLC accessors (bypass L1+L2): all cross-WG data.
__device__ __forceinline__ void st_bf16_sc(unsigned short* p, unsigned short v) {
  asm volatile("global_store_short %0, %1, off sc0 sc1"
               :: "v"((unsigned long long)p), "v"((unsigned)v) : "memory");
}
__device__ __forceinline__ void st_f32_sc(float* p, float v) {
  asm volatile("global_store_dword %0, %1, off sc0 sc1"
               :: "v"((unsigned long long)p), "v"(v) : "memory");
}

// ---- point-to-point epoch flags (single writer per 64B line, monotonic).
// Writer: [data sc1 stores] -> vmcnt(0) -> __syncthreads -> relaxed agent store.
// Reader: relaxed agent poll -> sc1 data loads. (Protocol proven R3/R5/R6.)
__device__ __forceinline__ void flag_store(unsigned* line, unsigned v) {
  __hip_atomic_store(line, v, __ATOMIC_RELAXED, __HIP_MEMORY_SCOPE_AGENT);
}
// Predicated per-lane poll: lanes with act=false pass trivially.
__device__ __forceinline__ void poll_pred(const unsigned* p, bool act, unsigned tgt) {
  int tries = 0;
  for (;;) {
    unsigned v = tgt;
    if (act) v = __hip_atomic_load(p, __ATOMIC_RELAXED, __HIP_MEMORY_SCOPE_AGENT);
    if (__all((int)(v >= tgt))) break;
    __builtin_amdgcn_s_sleep(1);
    if (++tries > (1 << 20)) break;   // deadlock valve; never hit normally
  }
}

// Fragment-order flat offset for [32 rows][1024 k] bf16 stored [mt][ks][lane][j].
__device__ __forceinline__ int frag_off(int m, int k) {
  const int mt = m >> 4, ks = k >> 5, kk = k & 31;
  const int l = (m & 15) + (((kk >> 2) & 3) << 4);
  const int j = (kk & 3) + ((kk >> 4) << 2);
  return ((mt * 32 + ks) * 64 + l) * 8 + j;
}

// Build A-fragments for x_t from global f32 (read-only input: plain cached loads).
template <int KS>
__device__ __forceinline__ void build_xfrags(const float* __restrict__ x, int t,
                                             int kbase, int lane,
                                             short8v frag[2][KS]) {
#pragma unroll
  for (int mt = 0; mt < 2; ++mt) {
    const int m = mt * 16 + (lane & 15);
    const float* row = x + ((size_t)m * T_ + t) * D_;
#pragma unroll
    for (int ks = 0; ks < KS; ++ks) {
      const int k0 = kbase + ks * 32 + ((lane >> 4) << 2);
      f32x4 lo = *(const f32x4*)(row + k0);
      f32x4 hi = *(const f32x4*)(row + k0 + 16);
      frag[mt][ks] = pack_frag(lo, hi);
    }
  }
}

// MFMA over KS k-steps, A from registers; B from LDS (frag order, hi/lo split).
template <int KS>
__device__ __forceinline__ void mfma_reg(const short8v frag[2][KS],
                                         const unsigned short* __restrict__ ldsW,
                                         int ksg0, f32x4* acc, int lane) {
#pragma unroll
  for (int mt = 0; mt < 2; ++mt)
#pragma unroll
    for (int ks = 0; ks < KS; ++ks) {
      const int ksg = ksg0 + ks;
      short8v bhi = *(const short8v*)(ldsW + ((size_t)(0 * 64 + ksg) * 64 + lane) * 8);
      short8v blo = *(const short8v*)(ldsW + ((size_t)(1 * 64 + ksg) * 64 + lane) * 8);
      acc[mt] = __builtin_amdgcn_mfma_f32_16x16x32_bf16(frag[mt][ks], bhi, acc[mt], 0, 0, 0);
      acc[mt] = __builtin_amdgcn_mfma_f32_16x16x32_bf16(frag[mt][ks], blo, acc[mt], 0, 0, 0);
    }
}

__global__ __launch_bounds__(TPB, 1) void gru_persistent(
    const float* __restrict__ x, const float* __restrict__ h0,
    const float* __restrict__ Wg, const float* __restrict__ bg,
    const float* __restrict__ Wc, const float* __restrict__ bc,
    float* __restrict__ out,
    unsigned* __restrict__ ctrs,
    unsigned short* __restrict__ hq,     // [frag 32x1024] bf16 h
    unsigned short* __restrict__ rhq,    // [frag 32x1024] bf16 r*h
    float* __restrict__ u_buf,           // [32][1024] f32 u gate
    float* __restrict__ h_buf)           // TRANSPOSED [1024 col][32 b] f32 h
{
  const int wg = blockIdx.x;
  const int tid = threadIdx.x;
  const int lane = tid & 63;
  const int wv = tid >> 6;

  extern __shared__ char smem[];
  unsigned short* ldsW = (unsigned short*)smem;            // [2][64][64][8]
  float* ldsR = (float*)(smem + 131072);                   // [8][256]
  float* ldsBias = (float*)(smem + 131072 + 8192);         // [16]
  float* ldsH = (float*)(smem + 131072 + 8192 + 64);       // [16][33]

  unsigned* flagH = ctrs;                  // 64 lines: cand WG j -> h(t) epochs
  unsigned* flagG = ctrs + 64 * 16;        // 128 lines: gate WG i -> rhq/u epochs

  const bool is_gate = wg < NGATE;
  const int c0 = (is_gate ? wg : (wg - NGATE)) * 16;
  const float* Wsrc = is_gate ? Wg : Wc;
  const int ldw = is_gate ? 2 * N_ : N_;
  const float* bias = is_gate ? bg : bc;

  const int col = tid & 15, row = tid >> 4;
  const int colg = c0 + col;
  const int b0 = row, b1 = 16 + row;

  // ---- preload weight slice into LDS in MFMA-fragment order, hi/lo split bf16
  for (int i = tid; i < 64 * 64; i += TPB) {
    const int ks = i >> 6, l = i & 63;
    const int n = l & 15, kqp = (l >> 4) * 4;
#pragma unroll
    for (int j = 0; j < 8; ++j) {
      const int k = ks * 32 + ((j < 4) ? 0 : 16) + kqp + (j & 3);
      const float w = Wsrc[(size_t)k * ldw + c0 + n];
      const unsigned short hi = f2bf(w);
      const unsigned short lo = f2bf(w - bf2f(hi));
      ldsW[((size_t)(0 * 64 + ks) * 64 + l) * 8 + j] = hi;
      ldsW[((size_t)(1 * 64 + ks) * 64 + l) * 8 + j] = lo;
    }
  }
  if (tid < 16) ldsBias[tid] = bias[c0 + tid];
  __syncthreads();

  if (is_gate) {
    const bool r_wg = (c0 < N_);
    unsigned* myflag = flagG + (size_t)wg * 16;
    // per-lane producer line: lanes 0-15 -> hq producers (cand 16wv+lane);
    // lane 16 (r-WGs only) -> cand WG 'wg' (writes h_buf cols [c0,c0+16))
    const unsigned* pollp = nullptr; bool pact = false;
    if (lane < 16)                { pollp = flagH + (size_t)(16 * wv + lane) * 16; pact = true; }
    else if (lane == 16 && r_wg)  { pollp = flagH + (size_t)wg * 16;               pact = true; }

    // partA (x @ Wg_x, K=256/wave) parked in accA across the flag boundary
    f32x4 accA[2] = {{0.f,0.f,0.f,0.f},{0.f,0.f,0.f,0.f}};
    {
      short8v xf[2][8];
      build_xfrags<8>(x, 0, wv * 256, lane, xf);
      mfma_reg<8>(xf, ldsW, wv * 8, accA, lane);
    }
    for (int t = 0; t < T_; ++t) {
      poll_pred(pollp, pact, (unsigned)(t + 1));     // h(t-1) slices ready
      // ---- one issue-batch: optional h dwordx4 (threads 0-127, r-WGs) + 16 hq
      f32x4 hvec = {0.f,0.f,0.f,0.f};
      const bool do_h = r_wg && (tid < 128);
      if (do_h) {
        const float* hsrc = h_buf + (size_t)(c0 + (tid & 15)) * 32 + (tid >> 4) * 4;
        asm volatile("global_load_dwordx4 %0, %1, off sc0 sc1"
                     : "=v"(hvec) : "v"((unsigned long long)hsrc) : "memory");
      }
      short8v areg[2][8];
#pragma unroll
      for (int mt = 0; mt < 2; ++mt)
#pragma unroll
        for (int ks = 0; ks < 8; ++ks) {
          const unsigned short* p =
              hq + ((size_t)((mt * 32 + wv * 8 + ks) * 64 + lane)) * 8;
          asm volatile("global_load_dwordx4 %0, %1, off sc0 sc1"
                       : "=v"(areg[mt][ks]) : "v"((unsigned long long)p) : "memory");
        }
      asm volatile("s_waitcnt vmcnt(0)" ::: "memory");
      __builtin_amdgcn_sched_barrier(0);             // rule #18
      if (do_h) {                                    // stage h for epilogue
        float* d = ldsH + (tid & 15) * 33 + (tid >> 4) * 4;
        d[0] = hvec[0]; d[1] = hvec[1]; d[2] = hvec[2]; d[3] = hvec[3];
      }
      // h-part MFMAs accumulate into the parked x-part
#pragma unroll
      for (int mt = 0; mt < 2; ++mt)
#pragma unroll
        for (int ks = 0; ks < 8; ++ks) {
          const int ksg = 32 + wv * 8 + ks;
          short8v bhi = *(const short8v*)(ldsW + ((size_t)(0 * 64 + ksg) * 64 + lane) * 8);
          short8v blo = *(const short8v*)(ldsW + ((size_t)(1 * 64 + ksg) * 64 + lane) * 8);
          accA[mt] = __builtin_amdgcn_mfma_f32_16x16x32_bf16(areg[mt][ks], bhi, accA[mt], 0, 0, 0);
          accA[mt] = __builtin_amdgcn_mfma_f32_16x16x32_bf16(areg[mt][ks], blo, accA[mt], 0, 0, 0);
        }
#pragma unroll
      for (int mt = 0; mt < 2; ++mt)
#pragma unroll
        for (int r = 0; r < 4; ++r)
          ldsR[(wv * 2 + mt) * 256 + (4 * (lane >> 4) + r) * 16 + (lane & 15)] = accA[mt][r];
      __syncthreads();
      {
        float s0 = ldsR[0 * 256 + tid] + ldsR[2 * 256 + tid]
                 + ldsR[4 * 256 + tid] + ldsR[6 * 256 + tid];
        float s1 = ldsR[1 * 256 + tid] + ldsR[3 * 256 + tid]
                 + ldsR[5 * 256 + tid] + ldsR[7 * 256 + tid];
        float p0 = fminf(fmaxf(s0 + ldsBias[col], -30.f), 30.f);
        float p1 = fminf(fmaxf(s1 + ldsBias[col], -30.f), 30.f);
        const float g0 = 1.f / (1.f + __expf(-p0));
        const float g1 = 1.f / (1.f + __expf(-p1));
        if (r_wg) {
          const float hv0 = ldsH[col * 33 + row];
          const float hv1 = ldsH[col * 33 + row + 16];
          st_bf16_sc(rhq + frag_off(b0, colg), f2bf(g0 * hv0));
          st_bf16_sc(rhq + frag_off(b1, colg), f2bf(g1 * hv1));
        } else {
          st_f32_sc(u_buf + b0 * N_ + (colg - N_), g0);
          st_f32_sc(u_buf + b1 * N_ + (colg - N_), g1);
        }
      }
      asm volatile("s_waitcnt vmcnt(0)" ::: "memory");
      __syncthreads();
      if (tid == 0) flag_store(myflag, (unsigned)(t + 1));
      if (t + 1 < T_) {                  // shadow: partA(t+1) during cand phase
        accA[0] = (f32x4){0.f,0.f,0.f,0.f};
        accA[1] = (f32x4){0.f,0.f,0.f,0.f};
        short8v xf[2][8];
        build_xfrags<8>(x, t + 1, wv * 256, lane, xf);
        mfma_reg<8>(xf, ldsW, wv * 8, accA, lane);
      }
    }
  } else {
    const int cidx = wg - NGATE;          // 0..63
    unsigned* myflag = flagH + (size_t)cidx * 16;
    // stage-1 (load producers): lanes 0-15 -> r-gates 16wv+lane; lane 16 -> u-gate 64+cidx
    const unsigned* p1 = nullptr; bool a1 = false;
    if (lane < 16)       { p1 = flagG + (size_t)(16 * wv + lane) * 16;  a1 = true; }
    else if (lane == 16) { p1 = flagG + (size_t)(64 + cidx) * 16;       a1 = true; }
    // stage-2 (write-guard): u-gates 64+16wv+lane — collectively all 128 gates
    const unsigned* p2 = nullptr; bool a2 = false;
    if (lane < 16)       { p2 = flagG + (size_t)(64 + 16 * wv + lane) * 16; a2 = true; }

    // ---- init h(-1)=h0: regs + transposed h_buf + hq frags; publish flag=1
    float hreg0 = h0[b0 * N_ + colg];
    float hreg1 = h0[b1 * N_ + colg];
    st_f32_sc(h_buf + (size_t)colg * 32 + b0, hreg0);
    st_f32_sc(h_buf + (size_t)colg * 32 + b1, hreg1);
    st_bf16_sc(hq + frag_off(b0, colg), f2bf(hreg0));
    st_bf16_sc(hq + frag_off(b1, colg), f2bf(hreg1));
    asm volatile("s_waitcnt vmcnt(0)" ::: "memory");
    __syncthreads();
    if (tid == 0) flag_store(myflag, 1u);

    f32x4 accA[2] = {{0.f,0.f,0.f,0.f},{0.f,0.f,0.f,0.f}};
    {  // partA(t=0): x0 @ Wc_x
      short8v xf[2][8];
      build_xfrags<8>(x, 0, wv * 256, lane, xf);
      mfma_reg<8>(xf, ldsW, wv * 8, accA, lane);
    }
    for (int t = 0; t < T_; ++t) {
      poll_pred(p1, a1, (unsigned)(t + 1));          // rhq slices + my u ready
      float uv0, uv1;
      asm volatile("global_load_dword %0, %2, off sc0 sc1\n\t"
                   "global_load_dword %1, %3, off sc0 sc1"
                   : "=&v"(uv0), "=&v"(uv1)
                   : "v"((unsigned long long)(u_buf + b0 * N_ + colg)),
                     "v"((unsigned long long)(u_buf + b1 * N_ + colg))
                   : "memory");
      short8v areg[2][8];
#pragma unroll
      for (int mt = 0; mt < 2; ++mt)
#pragma unroll
        for (int ks = 0; ks < 8; ++ks) {
          const unsigned short* p =
              rhq + ((size_t)((mt * 32 + wv * 8 + ks) * 64 + lane)) * 8;
          asm volatile("global_load_dwordx4 %0, %1, off sc0 sc1"
                       : "=v"(areg[mt][ks]) : "v"((unsigned long long)p) : "memory");
        }
      asm volatile("s_waitcnt vmcnt(0)" ::: "memory");
      __builtin_amdgcn_sched_barrier(0);
#pragma unroll
      for (int mt = 0; mt < 2; ++mt)
#pragma unroll
        for (int ks = 0; ks < 8; ++ks) {
          const int ksg = 32 + wv * 8 + ks;
          short8v bhi = *(const short8v*)(ldsW + ((size_t)(0 * 64 + ksg) * 64 + lane) * 8);
          short8v blo = *(const short8v*)(ldsW + ((size_t)(1 * 64 + ksg) * 64 + lane) * 8);
          accA[mt] = __builtin_amdgcn_mfma_f32_16x16x32_bf16(areg[mt][ks], bhi, accA[mt], 0, 0, 0);
          accA[mt] = __builtin_amdgcn_mfma_f32_16x16x32_bf16(areg[mt][ks], blo, accA[mt], 0, 0, 0);
        }
      poll_pred(p2, a2, (unsigned)(t + 1));          // all gates done reading hq(t-1)
#pragma unroll
      for (int mt = 0; mt < 2; ++mt)
#pragma unroll
        for (int r = 0; r < 4; ++r)
          ldsR[(wv * 2 + mt) * 256 + (4 * (lane >> 4) + r) * 16 + (lane & 15)] = accA[mt][r];
      __syncthreads();
      {
        float s0 = ldsR[0 * 256 + tid] + ldsR[2 * 256 + tid]
                 + ldsR[4 * 256 + tid] + ldsR[6 * 256 + tid];
        float s1 = ldsR[1 * 256 + tid] + ldsR[3 * 256 + tid]
                 + ldsR[5 * 256 + tid] + ldsR[7 * 256 + tid];
        float p0 = fminf(fmaxf(s0 + ldsBias[col], -20.f), 20.f);
        float p1v = fminf(fmaxf(s1 + ldsBias[col], -20.f), 20.f);
        const float e0 = __expf(2.f * p0), e1 = __expf(2.f * p1v);
        const float c0v = (e0 - 1.f) / (e0 + 1.f);   // tanh
        const float c1v = (e1 - 1.f) / (e1 + 1.f);
        const float hn0 = uv0 * hreg0 + (1.f - uv0) * c0v;
        const float hn1 = uv1 * hreg1 + (1.f - uv1) * c1v;
        hreg0 = hn0; hreg1 = hn1;
        st_bf16_sc(hq + frag_off(b0, colg), f2bf(hn0));
        st_bf16_sc(hq + frag_off(b1, colg), f2bf(hn1));
        st_f32_sc(h_buf + (size_t)colg * 32 + b0, hn0);
        st_f32_sc(h_buf + (size_t)colg * 32 + b1, hn1);
        out[((size_t)b0 * T_ + t) * N_ + colg] = hn0;   // cached (host-only reader)
        out[((size_t)b1 * T_ + t) * N_ + colg] = hn1;
      }
      asm volatile("s_waitcnt vmcnt(0)" ::: "memory");
      __syncthreads();
      if (tid == 0) flag_store(myflag, (unsigned)(t + 2));
      if (t + 1 < T_) {                  // shadow: partA(t+1) during gate phase
        accA[0] = (f32x4){0.f,0.f,0.f,0.f};
        accA[1] = (f32x4){0.f,0.f,0.f,0.f};
        short8v xf[2][8];
        build_xfrags<8>(x, t + 1, wv * 256, lane, xf);
        mfma_reg<8>(xf, ldsW, wv * 8, accA, lane);
      }
    }
  }
}

extern "C" void kernel_launch(void* const* d_in, const int* in_sizes, int n_in,
                              void* d_out, int out_size, void* d_ws, size_t ws_size,
                              hipStream_t stream) {
  const float* x  = (const float*)d_in[0];
  const float* h0 = (const float*)d_in[1];
  const float* Wg = (const float*)d_in[2];
  const float* bg = (const float*)d_in[3];
  const float* Wc = (const float*)d_in[4];
  const float* bc = (const float*)d_in[5];
  float* out = (float*)d_out;

  char* w = (char*)d_ws;
  unsigned* ctrs       = (unsigned*)(w + 0);             // 192 lines*64B = 12288 (reserve 16384)
  unsigned short* hq   = (unsigned short*)(w + 16384);   // 65536
  unsigned short* rhq  = (unsigned short*)(w + 81920);   // 65536
  float* u_buf         = (float*)(w + 147456);           // 131072
  float* h_buf         = (float*)(w + 278528);           // 131072 -> total 409600 B

  hipFuncSetAttribute((const void*)gru_persistent,
                      hipFuncAttributeMaxDynamicSharedMemorySize, SMEM_BYTES);
  hipMemsetAsync(w, 0, 16384, stream);  // zero flag lines each launch
  gru_persistent<<<NWG, TPB, SMEM_BYTES, stream>>>(
      x, h0, Wg, bg, Wc, bc, out, ctrs, hq, rhq, u_buf, h_buf);
}